// Round 7
// baseline (769.999 us; speedup 1.0000x reference)
//
#include <hip/hip_runtime.h>

// FELDMSTM: fused AutoCorrelationLayer(FourierBlock) + FFTDecompLayer
// B=8 N=2000 L=96 D=32 H=4 E=8 modes={1,4,5} kavg=25, float32 in/out.
//
// Math folding (exact):
//   q-bias drops (sum of cos/sin over full period = 0); k,v projections unused.
//   CS[d][m]   = sum_l x[l,d] * {cos,sin}(2*pi*m*l/96)        (forward basis)
//   X[c][m]    = sum_d Wq[c,d] * CS[d][m]   (Xre = Wq*Cx, Xim = -Wq*Sx)
//   O[h,o][m]  = sum_e X[h*8+e][m] * (W1 + i*W2)[n,h,e,o,m]
//   Z[d][m]    = sum_c Wo[d,c] * O[c][m]
//   new_x[l,d] = (1/48) * sum_m (Zre*cos - Zim*sin) + bo[d]
//   xr = x + new_x;  trend = 25-tap edge-padded mean;  res = xr - trend.
//
// R6 vs R4 (148.5us/dispatch anchor; R5's T-table regressed via +144MB HBM
// fetch and is reverted): R4 phases kept VERBATIM; the launch structure
// becomes persistent-per-node. tile = b*2000+n, so a block that owns node n
// and loops b=0..B-1 reuses W1/W2 (staged once), basis (sincos once), and
// PREFETCHES the next tile's x into registers during the solo phase
// (~2500cy of cover for the ~900cy HBM load) -- removing the per-tile
// x-load stall from the critical path. One extra barrier per tile (pp
// aliases xT, next B must wait for G). Grid 16000 -> 2000 blocks.

#define N_NODES 2000

__global__ __launch_bounds__(256, 4)
void fused_fourier_decomp(const float* __restrict__ x,
                          const float* __restrict__ Wq,
                          const float* __restrict__ Wo,
                          const float* __restrict__ bo,
                          const float* __restrict__ W1,
                          const float* __restrict__ W2,
                          float* __restrict__ out,
                          const int tiles)
{
  // xT: xr staging, stride 97 -> bank (d+l)%32, conflict-free column sweeps.
  // Aliases inside xT (all dead before phase F first writes xT):
  //   pp  = xT[0..1535]     phase-B partials (dead after solo reduce)
  //   csb = xT[1600..1791]  [6][32] raw CS (cos|sin, j-major)
  //   xsb = xT[1792..1983]  [6][32] X (sign-applied, j-major)
  //   osb = csb             [6][32] O (reuse after C's last csb read)
  __shared__ __align__(16) float xT[32 * 97];     // 12416 B
  __shared__ __align__(16) float basis[96 * 8];   // [l][0..2]=cos_m, [3..5]=sin_m
  __shared__ __align__(16) float W12_s[32 * 68];  // [cp][e][w1m0..2,w2m0..2,pad2]
  __shared__ __align__(16) float Z_s[32 * 8];     // [dout][0..2]=re, [3..5]=im
  __shared__ float bo_s[32];
  float* const pp  = xT;
  float* const csb = xT + 1600;
  float* const xsb = xT + 1792;
  float* const osb = xT + 1600;   // alias csb

  const int t = threadIdx.x;
  const int n = blockIdx.x;             // block owns node n, all batches
  const int d = t & 31;                 // owned channel / column
  const int g = t >> 5;                 // l-chunk 0..7 (12 rows each)
  const int l0 = g * 12;

  // ---- ONCE PER BLOCK: stage W1/W2 interleaved for phase-D vector reads
  // src i = h*192 + e*24 + o*3 + m  ->  dst = (h*8+o)*68 + e*8 + m (+3 for W2)
  {
    const float* W1p = W1 + (size_t)n * 768;
    const float* W2p = W2 + (size_t)n * 768;
    for (int i = t; i < 768; i += 256) {
      const int m = i % 3;
      const int o = (i / 3) & 7;
      const int e = (i / 24) & 7;
      const int h = i / 192;
      const int dst = (h * 8 + o) * 68 + e * 8 + m;
      W12_s[dst]     = W1p[i];
      W12_s[dst + 3] = W2p[i];
    }
  }
  if (t < 32) bo_s[t] = bo[t];

  // ---- ONCE PER BLOCK: cos/sin basis (exact integer angle reduction)
  if (t < 96) {
    const int modes[3] = {1, 4, 5};
#pragma unroll
    for (int m = 0; m < 3; ++m) {
      int r = (modes[m] * t) % 96;
      float ang = (float)r * (6.28318530717958647692f / 96.0f);
      float sv, cv;
      sincosf(ang, &sv, &cv);
      basis[t * 8 + m] = cv;
      basis[t * 8 + 3 + m] = sv;
    }
    basis[t * 8 + 6] = 0.0f;
    basis[t * 8 + 7] = 0.0f;
  }

  // ---- prefetch x for first tile (tile = n)
  float xv[12];
  if (n < tiles) {
    const float* xp = x + (size_t)n * (96 * 32);
#pragma unroll
    for (int i = 0; i < 12; ++i)
      xv[i] = xp[(size_t)(l0 + i) * 32 + d];
  }
  __syncthreads();   // staging + basis ready

  for (int b = 0; b * N_NODES + n < tiles; ++b) {
    const size_t tile = (size_t)b * N_NODES + n;
    const size_t base = tile * (96 * 32);

    // ---- phase B: partial CS over own 12 rows (x from registers)
    {
      float a0 = 0.f, a1 = 0.f, a2 = 0.f, a3 = 0.f, a4 = 0.f, a5 = 0.f;
#pragma unroll
      for (int i = 0; i < 12; ++i) {
        const int l = l0 + i;
        const float4 b0 = *(const float4*)&basis[l * 8];
        const float2 b1 = *(const float2*)&basis[l * 8 + 4];
        const float v = xv[i];
        a0 = fmaf(v, b0.x, a0);
        a1 = fmaf(v, b0.y, a1);
        a2 = fmaf(v, b0.z, a2);
        a3 = fmaf(v, b0.w, a3);
        a4 = fmaf(v, b1.x, a4);
        a5 = fmaf(v, b1.y, a5);
      }
      pp[g * 192 + 0 * 32 + d] = a0;
      pp[g * 192 + 1 * 32 + d] = a1;
      pp[g * 192 + 2 * 32 + d] = a2;
      pp[g * 192 + 3 * 32 + d] = a3;
      pp[g * 192 + 4 * 32 + d] = a4;
      pp[g * 192 + 5 * 32 + d] = a5;
    }
    __syncthreads();   // pp ready

    // ---- prefetch next tile's x (hidden under solo section + F)
    float xv2[12];
    const bool havenext = (tile + N_NODES) < (size_t)tiles;
    if (havenext) {
      const float* xp = x + base + (size_t)N_NODES * (96 * 32);
#pragma unroll
      for (int i = 0; i < 12; ++i)
        xv2[i] = xp[(size_t)(l0 + i) * 32 + d];
    }

    // ---- wave-0 solo spectral section: reduce -> C -> D -> E (verbatim R4)
    if (t < 64) {
      const int c  = t & 31;
      const int jj = t >> 5;

      // reduce: csb[j][c] = sum_g pp[g][j][c]  (48 lanes x 8 ds_read_b128)
      if (t < 48) {
        const int j = t >> 3, cq = t & 7;
        float4 acc = make_float4(0.f, 0.f, 0.f, 0.f);
#pragma unroll
        for (int gg = 0; gg < 8; ++gg) {
          const float4 p = *(const float4*)&pp[gg * 192 + j * 32 + cq * 4];
          acc.x += p.x; acc.y += p.y; acc.z += p.z; acc.w += p.w;
        }
        *(float4*)&csb[j * 32 + cq * 4] = acc;
      }
      __builtin_amdgcn_wave_barrier();

      // phase C: X = Wq * CS ; Xim picks up the rfft minus sign.
      {
        const float* wqr = Wq + c * 32;
        float4 wq4[8];
#pragma unroll
        for (int q = 0; q < 8; ++q) wq4[q] = *(const float4*)&wqr[q * 4];
        const int jb = jj * 3;
        float X0 = 0.f, X1 = 0.f, X2 = 0.f;
#pragma unroll
        for (int q = 0; q < 8; ++q) {
          const float4 w  = wq4[q];
          const float4 c0 = *(const float4*)&csb[(jb + 0) * 32 + q * 4];
          const float4 c1 = *(const float4*)&csb[(jb + 1) * 32 + q * 4];
          const float4 c2 = *(const float4*)&csb[(jb + 2) * 32 + q * 4];
          X0 = fmaf(w.x, c0.x, X0); X0 = fmaf(w.y, c0.y, X0);
          X0 = fmaf(w.z, c0.z, X0); X0 = fmaf(w.w, c0.w, X0);
          X1 = fmaf(w.x, c1.x, X1); X1 = fmaf(w.y, c1.y, X1);
          X1 = fmaf(w.z, c1.z, X1); X1 = fmaf(w.w, c1.w, X1);
          X2 = fmaf(w.x, c2.x, X2); X2 = fmaf(w.y, c2.y, X2);
          X2 = fmaf(w.z, c2.z, X2); X2 = fmaf(w.w, c2.w, X2);
        }
        const float sgn = jj ? -1.f : 1.f;
        xsb[(jb + 0) * 32 + c] = sgn * X0;
        xsb[(jb + 1) * 32 + c] = sgn * X1;
        xsb[(jb + 2) * 32 + c] = sgn * X2;
      }
      __builtin_amdgcn_wave_barrier();

      // phase D: per-head complex contraction over e (einsum bnhem,nheom).
      {
        const int h = (t >> 3) & 3;
        const int o = t & 7;
        const int cp = h * 8 + o;
        const float* wrow = &W12_s[cp * 68];
        float od0 = 0.f, od1 = 0.f, od2 = 0.f;

#define DSTEP(XC, E_) do {                                                  \
        const float4 wa = *(const float4*)&wrow[(E_) * 8];     /* w1m0..2,w2m0 */ \
        const float2 wb = *(const float2*)&wrow[(E_) * 8 + 4]; /* w2m1,w2m2 */    \
        { const float a = jj ? wa.x : -wa.w; const float b = jj ? wa.w : wa.x;    \
          od0 = fmaf(xr0.XC, b, fmaf(xi0.XC, a, od0)); }                          \
        { const float a = jj ? wa.y : -wb.x; const float b = jj ? wb.x : wa.y;    \
          od1 = fmaf(xr1.XC, b, fmaf(xi1.XC, a, od1)); }                          \
        { const float a = jj ? wa.z : -wb.y; const float b = jj ? wb.y : wa.z;    \
          od2 = fmaf(xr2.XC, b, fmaf(xi2.XC, a, od2)); }                          \
      } while (0)

        {  // e = 0..3
          const float4 xr0 = *(const float4*)&xsb[0 * 32 + h * 8];
          const float4 xr1 = *(const float4*)&xsb[1 * 32 + h * 8];
          const float4 xr2 = *(const float4*)&xsb[2 * 32 + h * 8];
          const float4 xi0 = *(const float4*)&xsb[3 * 32 + h * 8];
          const float4 xi1 = *(const float4*)&xsb[4 * 32 + h * 8];
          const float4 xi2 = *(const float4*)&xsb[5 * 32 + h * 8];
          DSTEP(x, 0); DSTEP(y, 1); DSTEP(z, 2); DSTEP(w, 3);
        }
        {  // e = 4..7
          const float4 xr0 = *(const float4*)&xsb[0 * 32 + h * 8 + 4];
          const float4 xr1 = *(const float4*)&xsb[1 * 32 + h * 8 + 4];
          const float4 xr2 = *(const float4*)&xsb[2 * 32 + h * 8 + 4];
          const float4 xi0 = *(const float4*)&xsb[3 * 32 + h * 8 + 4];
          const float4 xi1 = *(const float4*)&xsb[4 * 32 + h * 8 + 4];
          const float4 xi2 = *(const float4*)&xsb[5 * 32 + h * 8 + 4];
          DSTEP(x, 4); DSTEP(y, 5); DSTEP(z, 6); DSTEP(w, 7);
        }
#undef DSTEP

        osb[(jj * 3 + 0) * 32 + cp] = od0;
        osb[(jj * 3 + 1) * 32 + cp] = od1;
        osb[(jj * 3 + 2) * 32 + cp] = od2;
      }
      __builtin_amdgcn_wave_barrier();

      // phase E: Z = Wo * O (fold output projection into spectrum).
      {
        const float* wor = Wo + c * 32;
        float4 wo4[8];
#pragma unroll
        for (int q = 0; q < 8; ++q) wo4[q] = *(const float4*)&wor[q * 4];
        const int jb = jj * 3;
        float Z0 = 0.f, Z1 = 0.f, Z2 = 0.f;
#pragma unroll
        for (int q = 0; q < 8; ++q) {
          const float4 w  = wo4[q];
          const float4 o0 = *(const float4*)&osb[(jb + 0) * 32 + q * 4];
          const float4 o1 = *(const float4*)&osb[(jb + 1) * 32 + q * 4];
          const float4 o2 = *(const float4*)&osb[(jb + 2) * 32 + q * 4];
          Z0 = fmaf(w.x, o0.x, Z0); Z0 = fmaf(w.y, o0.y, Z0);
          Z0 = fmaf(w.z, o0.z, Z0); Z0 = fmaf(w.w, o0.w, Z0);
          Z1 = fmaf(w.x, o1.x, Z1); Z1 = fmaf(w.y, o1.y, Z1);
          Z1 = fmaf(w.z, o1.z, Z1); Z1 = fmaf(w.w, o1.w, Z1);
          Z2 = fmaf(w.x, o2.x, Z2); Z2 = fmaf(w.y, o2.y, Z2);
          Z2 = fmaf(w.z, o2.z, Z2); Z2 = fmaf(w.w, o2.w, Z2);
        }
        Z_s[c * 8 + jb + 0] = Z0;
        Z_s[c * 8 + jb + 1] = Z1;
        Z_s[c * 8 + jb + 2] = Z2;
      }
    }
    __syncthreads();   // Z_s ready

    // ---- phase F: irfft synthesis + out-bias + residual -> xr (regs + LDS)
    float xr[12];
    {
      const float4 z0 = *(const float4*)&Z_s[d * 8];     // (re0,re1,re2,im0)
      const float2 z1 = *(const float2*)&Z_s[d * 8 + 4]; // (im1,im2)
      const float bov = bo_s[d];
#pragma unroll
      for (int i = 0; i < 12; ++i) {
        const int l = l0 + i;
        const float4 b0 = *(const float4*)&basis[l * 8];     // (c0,c1,c2,s0)
        const float2 b1 = *(const float2*)&basis[l * 8 + 4]; // (s1,s2)
        const float v = z0.x * b0.x + z0.y * b0.y + z0.z * b0.z
                      - z0.w * b0.w - z1.x * b1.x - z1.y * b1.y;
        const float r = fmaf(v, (1.0f / 48.0f), bov) + xv[i];
        xr[i] = r;
        xT[d * 97 + l] = r;
      }
    }
    __syncthreads();   // xT ready

    // ---- phase G: 25-tap edge-padded moving average + store
    {
      const float* col = &xT[d * 97];
      float lowv[12];
      float S = 0.f;
#pragma unroll
      for (int j = 0; j < 12; ++j) {          // below-window taps (clamped)
        int idx = l0 - 12 + j;
        idx = idx < 0 ? 0 : idx;
        lowv[j] = col[idx];
        S += lowv[j];
      }
#pragma unroll
      for (int i = 0; i < 12; ++i) S += xr[i]; // own rows l0..l0+11
      {
        int idx = l0 + 12;                     // top tap of first window
        idx = idx > 95 ? 95 : idx;
        S += col[idx];
      }
#pragma unroll
      for (int i = 0; i < 12; ++i) {
        const int l = l0 + i;
        const float res = xr[i] - S * (1.0f / 25.0f);
        out[base + (size_t)l * 32 + d] = res;
        int hi = l + 13;
        hi = hi > 95 ? 95 : hi;
        S += col[hi] - lowv[i];
      }
    }
    __syncthreads();   // xT/pp free for next iteration's phase B

    // rotate prefetched x into place
#pragma unroll
    for (int i = 0; i < 12; ++i) xv[i] = xv2[i];
  }
}

extern "C" void kernel_launch(void* const* d_in, const int* in_sizes, int n_in,
                              void* d_out, int out_size, void* d_ws, size_t ws_size,
                              hipStream_t stream) {
  (void)n_in; (void)out_size; (void)d_ws; (void)ws_size;
  const float* x  = (const float*)d_in[0];
  const float* Wq = (const float*)d_in[1];
  // d_in[2]=bq (exactly cancelled), d_in[3..6]=Wk,bk,Wv,bv (unused by output)
  const float* Wo = (const float*)d_in[7];
  const float* bo = (const float*)d_in[8];
  const float* W1 = (const float*)d_in[9];
  const float* W2 = (const float*)d_in[10];
  float* out = (float*)d_out;

  const int tiles = in_sizes[0] / (96 * 32);  // B*N tiles of 96x32
  fused_fourier_decomp<<<N_NODES, 256, 0, stream>>>(x, Wq, Wo, bo, W1, W2, out,
                                                    tiles);
}